// Round 7
// baseline (221.547 us; speedup 1.0000x reference)
//
#include <hip/hip_runtime.h>

// Problem: D=512, H=8, L=4, NE=8, B=32, S=512. fp32 in / fp32 out.
//
// Reduction chain (R3-verified absmax 0.0, R4 3.8e-6, R6 6.1e-5):
//   cross-attn Sk=1 -> softmax==1 -> last[b] = (ctx[b]@cWv+cbv)@cWo+cbo,
//   ctx[b] = c0[b]*ctxW[0] + c1[b]*ctxW[1] + ctxb  -> batch factors out:
//     A_i = x_i@cWv (x={ctxW0,ctxW1,ctxb}), A2+=cbv
//     B_i = A_i@cWo, B2+=cbo
//     P_i[s,h] = B_i@spW[h][s], P2+=spb
//     out[b,h,o] = c0[b]*P0 + c1[b]*P1 + P2   (s=sid[b])
//
// R7: sync costs dominate (R5 coop +70us; R6 flag barriers ~= R4's graph
// gaps). So: ZERO cross-block sync. 16 blocks = one per (s,h); every block
// redundantly computes the full A and B chains in its own LDS (in-block
// __syncthreads only), then its 512x64 head + batch broadcast. ~4us, one
// regular dispatch, no ws use. Redundant 32MB of L2/LLC-warm weight reads
// overlap with VALU.

#define DD 512

__device__ __forceinline__ void fma4(float4& a, const float x, const float4 w) {
    a.x += x * w.x; a.y += x * w.y; a.z += x * w.z; a.w += x * w.w;
}

// yout[3*512] = xin[3*512] @ W (512x512 row-major); yout vec2 += bias2.
// wave w owns rows [w*128, w*128+128); lane owns 8 cols c0..c0+7.
__device__ __forceinline__ void gemv3_block(
    const float* __restrict__ W, const float* __restrict__ bias2,
    const float* xin, float* yout, float* red,
    const int t, const int w, const int lane, const int c0)
{
    const float* wp = W + (size_t)(w * 128) * DD + c0;
    float4 acc[3][2];
    #pragma unroll
    for (int i = 0; i < 3; ++i) {
        acc[i][0] = make_float4(0.f, 0.f, 0.f, 0.f);
        acc[i][1] = make_float4(0.f, 0.f, 0.f, 0.f);
    }
    const float* xp = xin + w * 128;
    #pragma unroll 8
    for (int d = 0; d < 128; ++d) {
        const float4 wA = *(const float4*)(wp);
        const float4 wB = *(const float4*)(wp + 4);
        wp += DD;
        const float x0 = xp[d];            // wave-uniform -> LDS broadcast
        const float x1 = xp[DD + d];
        const float x2 = xp[2 * DD + d];
        fma4(acc[0][0], x0, wA); fma4(acc[0][1], x0, wB);
        fma4(acc[1][0], x1, wA); fma4(acc[1][1], x1, wB);
        fma4(acc[2][0], x2, wA); fma4(acc[2][1], x2, wB);
    }
    #pragma unroll
    for (int i = 0; i < 3; ++i) {
        *(float4*)&red[w * 1536 + i * DD + c0]     = acc[i][0];
        *(float4*)&red[w * 1536 + i * DD + c0 + 4] = acc[i][1];
    }
    __syncthreads();
    #pragma unroll
    for (int r = 0; r < 6; ++r) {         // 1536 outputs, coalesced in LDS
        const int k = t + 256 * r;
        float v = red[k] + red[1536 + k] + red[3072 + k] + red[4608 + k];
        if (k >= 2 * DD) v += bias2[k - 2 * DD];
        yout[k] = v;
    }
    __syncthreads();
}

__global__ __launch_bounds__(256) void hivemind_allinone(
    const float* __restrict__ ctxW,   // (2,512)
    const float* __restrict__ ctxb,   // (512)
    const float* __restrict__ cWv,    // (512,512)
    const float* __restrict__ cbv,    // (512)
    const float* __restrict__ cWo,    // (512,512)
    const float* __restrict__ cbo,    // (512)
    const float* __restrict__ spWp,   // (8,512,64)
    const float* __restrict__ spbp,   // (8,64)
    const float* __restrict__ spWa,   // (8,512,64)
    const float* __restrict__ spba,   // (8,64)
    const float* __restrict__ ctxin,  // (32,2)
    const int*   __restrict__ sid,    // (32)
    float*       __restrict__ out)    // pred (32,64) then act (32,64)
{
    __shared__ float sx[3 * DD];
    __shared__ float sy[3 * DD];
    __shared__ float red[4 * 3 * DD];
    __shared__ float pv[3 * 64];
    __shared__ float sc0[32], sc1[32];
    __shared__ int   ssid[32];

    const int t    = threadIdx.x;
    const int s    = blockIdx.x & 7;
    const int h    = blockIdx.x >> 3;
    const int w    = t >> 6;         // wave id == d-group of 128 rows
    const int lane = t & 63;
    const int c0   = lane * 8;

    if (t < 32) {
        ssid[t] = sid[t];
        sc0[t]  = ctxin[2 * t];
        sc1[t]  = ctxin[2 * t + 1];
    }
    sx[t]            = ctxW[t];
    sx[t + 256]      = ctxW[t + 256];
    sx[DD + t]       = ctxW[DD + t];
    sx[DD + t + 256] = ctxW[DD + t + 256];
    sx[2 * DD + t]       = ctxb[t];
    sx[2 * DD + t + 256] = ctxb[t + 256];
    __syncthreads();

    // A = x @ cWv (+cbv)  then  B = A @ cWo (+cbo); result lands back in sx
    gemv3_block(cWv, cbv, sx, sy, red, t, w, lane, c0);
    gemv3_block(cWo, cbo, sy, sx, red, t, w, lane, c0);

    // head (s,h): P_i[o] = sum_d B_i[d] * spW[s][d][o]
    const float* W    = (h ? spWa : spWp) + (size_t)s * DD * 64;
    const float* bias = (h ? spba : spbp) + s * 64;
    {
        const float* wp = W + (size_t)(w * 128) * 64 + lane;
        const float* xp = sx + w * 128;
        float p0 = 0.f, p1 = 0.f, p2 = 0.f;
        #pragma unroll 8
        for (int d = 0; d < 128; ++d) {
            const float wv = *wp; wp += 64;   // 256B/wave coalesced
            p0 += xp[d] * wv;
            p1 += xp[DD + d] * wv;
            p2 += xp[2 * DD + d] * wv;
        }
        red[w * 192 + lane]       = p0;
        red[w * 192 + 64 + lane]  = p1;
        red[w * 192 + 128 + lane] = p2;
    }
    __syncthreads();
    if (t < 192) {
        float v = red[t] + red[192 + t] + red[384 + t] + red[576 + t];
        if (t >= 128) v += bias[t - 128];
        pv[t] = v;
    }
    __syncthreads();
    if (t < 64) {
        const float v0 = pv[t], v1 = pv[64 + t], v2 = pv[128 + t];
        #pragma unroll
        for (int b = 0; b < 32; ++b) {
            if (ssid[b] == s) {   // wave-uniform branch
                out[h * 2048 + b * 64 + t] = sc0[b] * v0 + sc1[b] * v1 + v2;
            }
        }
    }
}

extern "C" void kernel_launch(void* const* d_in, const int* in_sizes, int n_in,
                              void* d_out, int out_size, void* d_ws, size_t ws_size,
                              hipStream_t stream) {
    // 0 x_batch, 1 context_batch, 2 specialist_ids, 3 emb, 4-11 attn, 12-15 ln,
    // 16-19 ffn, 20 ctxW, 21 ctxb, 22-25 cWq/cWk, 26 cWv, 27 cbv, 28 cWo,
    // 29 cbo, 30 spWp, 31 spbp, 32 spWa, 33 spba
    const float* ctxin = (const float*)d_in[1];
    const int*   sid   = (const int*)d_in[2];
    const float* ctxW  = (const float*)d_in[20];
    const float* ctxb  = (const float*)d_in[21];
    const float* cWv   = (const float*)d_in[26];
    const float* cbv   = (const float*)d_in[27];
    const float* cWo   = (const float*)d_in[28];
    const float* cbo   = (const float*)d_in[29];
    const float* spWp  = (const float*)d_in[30];
    const float* spbp  = (const float*)d_in[31];
    const float* spWa  = (const float*)d_in[32];
    const float* spba  = (const float*)d_in[33];
    float* out = (float*)d_out;

    hivemind_allinone<<<dim3(16), dim3(256), 0, stream>>>(
        ctxW, ctxb, cWv, cbv, cWo, cbo,
        spWp, spbp, spWa, spba, ctxin, sid, out);
}

// Round 8
// 152.378 us; speedup vs baseline: 1.4539x; 1.4539x over previous
//
#include <hip/hip_runtime.h>

// Problem: D=512, H=8, L=4, NE=8, B=32, S=512. fp32 in / fp32 out.
//
// Reduction chain (R3-verified absmax 0.0, R4 3.8e-6):
//   cross-attn Sk=1 -> softmax==1 -> last[b] = (ctx[b]@cWv+cbv)@cWo+cbo,
//   ctx[b] = c0[b]*ctxW[0] + c1[b]*ctxW[1] + ctxb  -> batch factors out:
//     A_i = x_i@cWv (x={ctxW0,ctxW1,ctxb}), A2+=cbv
//     B_i = A_i@cWo, B2+=cbo
//     P_i[s,h] = B_i@spW[h][s], P2+=spb
//     out[b,h,o] = c0[b]*P0 + c1[b]*P1 + P2   (s=sid[b])
//
// Cost model (R3-R7 measured): harness restore+poison floor ~125us. Sync
// alternatives all lose: coop launch +70us (R5), in-kernel flag barriers
// ~= graph gaps (R6), per-block redundant compute = per-CU BW trap (R7:
// 32MB/16CU = 82us). So: R4's 3 small dispatches, latency-tuned:
//   - GEMV stages: 512 thr, 16 independent loads/thread (1 latency batch)
//   - heads: 64 blocks (32KB/block), 32 independent loads/thread

#define DD 512

// dst[vec*512+c] = sum_d x_vec[d]*W[d][c] (+bias2 for vec 2)
// grid 32 x 512 thr: block = 16-col slice; thread = (col, 16-row group)
__global__ __launch_bounds__(512) void stage_gemv3(
    const float* __restrict__ x0, const float* __restrict__ x1,
    const float* __restrict__ x2,
    const float* __restrict__ W,      // (512,512) row-major
    const float* __restrict__ bias2,  // (512)
    float*       __restrict__ dst)    // (3,512)
{
    __shared__ float sx[3 * DD];
    __shared__ float red[32][48];     // [dgroup][col*3+vec]
    const int t = threadIdx.x;
    const int cbase = blockIdx.x * 16;

    if (t < DD) {
        sx[t]          = x0[t];
        sx[DD + t]     = x1[t];
        sx[2 * DD + t] = x2[t];
    }
    __syncthreads();

    const int c = t & 15, dg = t >> 4;        // 16 cols x 32 d-groups of 16
    const float* wp = W + (size_t)(dg * 16) * DD + cbase + c;
    float wreg[16];
    #pragma unroll
    for (int j = 0; j < 16; ++j)              // 16 independent loads in flight
        wreg[j] = wp[(size_t)j * DD];
    float p0 = 0.f, p1 = 0.f, p2 = 0.f;
    #pragma unroll
    for (int j = 0; j < 16; ++j) {
        const int d = dg * 16 + j;
        p0 += sx[d] * wreg[j];
        p1 += sx[DD + d] * wreg[j];
        p2 += sx[2 * DD + d] * wreg[j];
    }
    red[dg][c * 3 + 0] = p0;
    red[dg][c * 3 + 1] = p1;
    red[dg][c * 3 + 2] = p2;
    __syncthreads();

    if (t < 48) {                             // 16 cols x 3 vecs
        const int cc = t / 3, vec = t % 3;
        float s = 0.f;
        #pragma unroll
        for (int g = 0; g < 32; ++g) s += red[g][t];
        if (vec == 2) s += bias2[cbase + cc];
        dst[vec * DD + cbase + cc] = s;
    }
}

// heads + batch broadcast. grid 64 (s=blk&7, h=(blk>>3)&1, q=blk>>4) x 256 thr
__global__ __launch_bounds__(256) void stage_heads(
    const float* __restrict__ Bv,     // (3,512)
    const float* __restrict__ spWp, const float* __restrict__ spbp,
    const float* __restrict__ spWa, const float* __restrict__ spba,
    const float* __restrict__ ctxin,  // (32,2)
    const int*   __restrict__ sid,    // (32)
    float*       __restrict__ out)    // pred (32,64) then act (32,64)
{
    __shared__ float sb[3 * DD];
    __shared__ float red[16][48];     // [dgroup][o16*3+vec]
    __shared__ float pv[48];
    __shared__ float sc0[32], sc1[32];
    __shared__ int   ssid[32];
    const int t = threadIdx.x;
    const int s = blockIdx.x & 7, h = (blockIdx.x >> 3) & 1, q = blockIdx.x >> 4;

    for (int i = t; i < 3 * DD; i += 256) sb[i] = Bv[i];
    if (t < 32) {
        ssid[t] = sid[t];
        sc0[t] = ctxin[2 * t];
        sc1[t] = ctxin[2 * t + 1];
    }
    __syncthreads();

    const float* W    = (h ? spWa : spWp) + (size_t)s * DD * 64;
    const float* bias = (h ? spba : spbp) + s * 64;
    const int o16 = t & 15, dg = t >> 4;      // 16 outs x 16 d-groups of 32
    const int o = q * 16 + o16;
    const float* wp = W + (size_t)(dg * 32) * 64 + o;
    float wreg[32];
    #pragma unroll
    for (int j = 0; j < 32; ++j)              // 32 independent loads in flight
        wreg[j] = wp[(size_t)j * 64];
    float p0 = 0.f, p1 = 0.f, p2 = 0.f;
    #pragma unroll
    for (int j = 0; j < 32; ++j) {
        const int d = dg * 32 + j;
        p0 += sb[d] * wreg[j];
        p1 += sb[DD + d] * wreg[j];
        p2 += sb[2 * DD + d] * wreg[j];
    }
    red[dg][o16 * 3 + 0] = p0;
    red[dg][o16 * 3 + 1] = p1;
    red[dg][o16 * 3 + 2] = p2;
    __syncthreads();

    if (t < 48) {
        const int oo = t / 3, vec = t % 3;
        float a = 0.f;
        #pragma unroll
        for (int g = 0; g < 16; ++g) a += red[g][t];
        if (vec == 2) a += bias[q * 16 + oo];
        pv[oo * 3 + vec] = a;
    }
    __syncthreads();

    if (t < 16) {
        const float v0 = pv[t * 3], v1 = pv[t * 3 + 1], v2 = pv[t * 3 + 2];
        #pragma unroll
        for (int b = 0; b < 32; ++b) {
            if (ssid[b] == s) {               // wave-uniform
                out[h * 2048 + b * 64 + q * 16 + t] =
                    sc0[b] * v0 + sc1[b] * v1 + v2;
            }
        }
    }
}

extern "C" void kernel_launch(void* const* d_in, const int* in_sizes, int n_in,
                              void* d_out, int out_size, void* d_ws, size_t ws_size,
                              hipStream_t stream) {
    // 0 x_batch, 1 context_batch, 2 specialist_ids, 3 emb, 4-11 attn, 12-15 ln,
    // 16-19 ffn, 20 ctxW, 21 ctxb, 22-25 cWq/cWk, 26 cWv, 27 cbv, 28 cWo,
    // 29 cbo, 30 spWp, 31 spbp, 32 spWa, 33 spba
    const float* ctxin = (const float*)d_in[1];
    const int*   sid   = (const int*)d_in[2];
    const float* ctxW  = (const float*)d_in[20];
    const float* ctxb  = (const float*)d_in[21];
    const float* cWv   = (const float*)d_in[26];
    const float* cbv   = (const float*)d_in[27];
    const float* cWo   = (const float*)d_in[28];
    const float* cbo   = (const float*)d_in[29];
    const float* spWp  = (const float*)d_in[30];
    const float* spbp  = (const float*)d_in[31];
    const float* spWa  = (const float*)d_in[32];
    const float* spba  = (const float*)d_in[33];
    float* out = (float*)d_out;
    float* wsA = (float*)d_ws;       // A[3][512]
    float* wsB = wsA + 3 * DD;       // B[3][512]

    stage_gemv3<<<dim3(32), dim3(512), 0, stream>>>(
        ctxW, ctxW + DD, ctxb, cWv, cbv, wsA);
    stage_gemv3<<<dim3(32), dim3(512), 0, stream>>>(
        wsA, wsA + DD, wsA + 2 * DD, cWo, cbo, wsB);
    stage_heads<<<dim3(64), dim3(256), 0, stream>>>(
        wsB, spWp, spbp, spWa, spba, ctxin, sid, out);
}